// Round 1
// baseline (408.438 us; speedup 1.0000x reference)
//
#include <hip/hip_runtime.h>

#define NN 8192
#define FF 64
#define NOUT 64
#define KS 8               // K-split: grid = 128 mtiles * 8 = 1024 blocks, 4/CU resident
#define KCHUNK (NN / KS)   // 1024
#define MROWS 64           // rows per block (one 16-row group per wave)

typedef __bf16 bf16x8 __attribute__((ext_vector_type(8)));
typedef float f32x4 __attribute__((ext_vector_type(4)));

__device__ inline bf16x8 cvt8(f32x4 a, f32x4 b) {
    bf16x8 r;
    #pragma unroll
    for (int i = 0; i < 4; ++i) { r[i] = (__bf16)a[i]; r[i + 4] = (__bf16)b[i]; }
    return r;
}

// One-shot: featT[f][n] = bf16(feat[n][f]).  1 MB output, L2-resident thereafter.
__global__ __launch_bounds__(256)
void transpose_kernel(const float* __restrict__ feat, __bf16* __restrict__ featT) {
    __shared__ __bf16 t[64][72];   // +8 pad
    int tid = threadIdx.x;
    int n0 = blockIdx.x * 64;
    {
        int r = tid >> 2, cg = (tid & 3) * 16;
        const float* p = feat + (size_t)(n0 + r) * FF + cg;
        f32x4 v0 = *(const f32x4*)(p);
        f32x4 v1 = *(const f32x4*)(p + 4);
        f32x4 v2 = *(const f32x4*)(p + 8);
        f32x4 v3 = *(const f32x4*)(p + 12);
        #pragma unroll
        for (int j = 0; j < 4; ++j) {
            t[r][cg + 0 + j]  = (__bf16)v0[j];
            t[r][cg + 4 + j]  = (__bf16)v1[j];
            t[r][cg + 8 + j]  = (__bf16)v2[j];
            t[r][cg + 12 + j] = (__bf16)v3[j];
        }
    }
    __syncthreads();
    int f = tid >> 2, seg = (tid & 3) * 16;
    bf16x8 o0, o1;
    #pragma unroll
    for (int i = 0; i < 8; ++i) { o0[i] = t[seg + i][f]; o1[i] = t[seg + 8 + i][f]; }
    *(bf16x8*)&featT[(size_t)f * NN + n0 + seg]     = o0;
    *(bf16x8*)&featT[(size_t)f * NN + n0 + seg + 8] = o1;
}

// adj streamed once (nontemporal), B-fragments straight from L2-resident featT.
// No LDS, no barriers. Rowsum(adj) via ones-col-0 B-frag MFMA (free).
__global__ __launch_bounds__(256, 4)
void main_kernel(const float* __restrict__ adj, const __bf16* __restrict__ featT,
                 __bf16* __restrict__ partN, float* __restrict__ partDeg) {
    int tid = threadIdx.x;
    int w = tid >> 6, lane = tid & 63, ln = lane & 15, q = lane >> 4;
    int ks = blockIdx.x & (KS - 1);   // blk%8 == XCD: each XCD reads ONE 128 KB featT slice
    int mt = blockIdx.x >> 3;         // 128 m-tiles of 64 rows

    int rowA = mt * MROWS + w * 16 + ln;
    const float* ap = adj + (size_t)rowA * NN + (size_t)ks * KCHUNK + q * 8;
    const __bf16* bbase = featT + (size_t)ln * NN + (size_t)ks * KCHUNK + q * 8;
    const __bf16* bp0 = bbase;
    const __bf16* bp1 = bbase + (size_t)16 * NN;
    const __bf16* bp2 = bbase + (size_t)32 * NN;
    const __bf16* bp3 = bbase + (size_t)48 * NN;

    f32x4 acc[4], accd;
    accd = 0;
    #pragma unroll
    for (int t = 0; t < 4; ++t) acc[t] = 0;

    bf16x8 ones;
    __bf16 o = (ln == 0) ? (__bf16)1.0f : (__bf16)0.0f;
    #pragma unroll
    for (int i = 0; i < 8; ++i) ones[i] = o;

    #pragma unroll 2
    for (int s = 0; s < KCHUNK / 32; ++s) {   // 32 iters, barrier-free
        f32x4 a0 = __builtin_nontemporal_load((const f32x4*)(ap + s * 32));
        f32x4 a1 = __builtin_nontemporal_load((const f32x4*)(ap + s * 32 + 4));
        bf16x8 b0 = *(const bf16x8*)(bp0 + s * 32);
        bf16x8 b1 = *(const bf16x8*)(bp1 + s * 32);
        bf16x8 b2 = *(const bf16x8*)(bp2 + s * 32);
        bf16x8 b3 = *(const bf16x8*)(bp3 + s * 32);
        bf16x8 af = cvt8(a0, a1);
        acc[0] = __builtin_amdgcn_mfma_f32_16x16x32_bf16(af, b0, acc[0], 0, 0, 0);
        acc[1] = __builtin_amdgcn_mfma_f32_16x16x32_bf16(af, b1, acc[1], 0, 0, 0);
        acc[2] = __builtin_amdgcn_mfma_f32_16x16x32_bf16(af, b2, acc[2], 0, 0, 0);
        acc[3] = __builtin_amdgcn_mfma_f32_16x16x32_bf16(af, b3, acc[3], 0, 0, 0);
        accd   = __builtin_amdgcn_mfma_f32_16x16x32_bf16(af, ones, accd, 0, 0, 0);
    }

    // C/D layout: col = ln, row(within 16-tile) = q*4 + r
    int grow = mt * MROWS + w * 16 + q * 4;
    #pragma unroll
    for (int r = 0; r < 4; ++r) {
        size_t base = ((size_t)(ks << 13) + grow + r) * FF + ln;
        partN[base +  0] = (__bf16)acc[0][r];
        partN[base + 16] = (__bf16)acc[1][r];
        partN[base + 32] = (__bf16)acc[2][r];
        partN[base + 48] = (__bf16)acc[3][r];
    }
    if (ln == 0) {
        #pragma unroll
        for (int r = 0; r < 4; ++r)
            partDeg[(ks << 13) + grow + r] = accd[r];
    }
}

// out = [feat | (sum_ks partN)/(sum_ks partDeg + 1)] @ W^T  via bf16 MFMA
__global__ __launch_bounds__(256)
void epilogue_kernel(const float* __restrict__ feat, const float* __restrict__ W,
                     const __bf16* __restrict__ partN, const float* __restrict__ partDeg,
                     float* __restrict__ out) {
    __shared__ __bf16 dataB[64][136];
    __shared__ float rdeg[64];
    int tid = threadIdx.x, blk = blockIdx.x;

    if (tid < 64) {
        float s = 0.f;
        #pragma unroll
        for (int ks = 0; ks < KS; ++ks) s += partDeg[(ks << 13) + blk * 64 + tid];
        rdeg[tid] = 1.0f / (s + 1.0f);
    }
    __syncthreads();

    #pragma unroll
    for (int i = 0; i < 2; ++i) {
        int idx = tid + i * 256;
        int r = idx >> 3, c = (idx & 7) * 8;
        float s[8];
        #pragma unroll
        for (int j = 0; j < 8; ++j) s[j] = 0.f;
        #pragma unroll
        for (int ks = 0; ks < KS; ++ks) {
            bf16x8 v = *(const bf16x8*)&partN[((size_t)(ks << 13) + blk * 64 + r) * FF + c];
            #pragma unroll
            for (int j = 0; j < 8; ++j) s[j] += (float)v[j];
        }
        float rd = rdeg[r];
        bf16x8 o;
        #pragma unroll
        for (int j = 0; j < 8; ++j) o[j] = (__bf16)(s[j] * rd);
        *(bf16x8*)&dataB[r][64 + c] = o;
    }
    #pragma unroll
    for (int i = 0; i < 2; ++i) {
        int idx = tid + i * 256;
        int r = idx >> 3, c = (idx & 7) * 8;
        const float* p = feat + (size_t)(blk * 64 + r) * FF + c;
        f32x4 f0 = *(const f32x4*)p;
        f32x4 f1 = *(const f32x4*)(p + 4);
        *(bf16x8*)&dataB[r][c] = cvt8(f0, f1);
    }
    __syncthreads();

    int w = tid >> 6, lane = tid & 63, ln = lane & 15, q = lane >> 4;
    f32x4 acc[4];
    #pragma unroll
    for (int t = 0; t < 4; ++t) acc[t] = 0;

    #pragma unroll
    for (int kk = 0; kk < 4; ++kk) {
        bf16x8 af = *(const bf16x8*)&dataB[w * 16 + ln][kk * 32 + q * 8];
        #pragma unroll
        for (int t = 0; t < 4; ++t) {
            const float* wp = W + (size_t)(t * 16 + ln) * 128 + kk * 32 + q * 8;
            f32x4 b0 = *(const f32x4*)wp;
            f32x4 b1 = *(const f32x4*)(wp + 4);
            bf16x8 bf = cvt8(b0, b1);
            acc[t] = __builtin_amdgcn_mfma_f32_16x16x32_bf16(af, bf, acc[t], 0, 0, 0);
        }
    }

    int grow = blk * 64 + w * 16 + q * 4;
    #pragma unroll
    for (int t = 0; t < 4; ++t)
        #pragma unroll
        for (int r = 0; r < 4; ++r)
            out[(size_t)(grow + r) * NOUT + t * 16 + ln] = acc[t][r];
}

extern "C" void kernel_launch(void* const* d_in, const int* in_sizes, int n_in,
                              void* d_out, int out_size, void* d_ws, size_t ws_size,
                              hipStream_t stream) {
    const float* adj  = (const float*)d_in[0];
    const float* feat = (const float*)d_in[1];
    const float* W    = (const float*)d_in[2];
    float* out = (float*)d_out;
    char* ws = (char*)d_ws;

    // ws: partN 8MB (KS*8192*64 bf16) | partDeg 256KB | featT 1MB
    __bf16* partN   = (__bf16*)ws;
    float*  partDeg = (float*)(ws + (size_t)KS * NN * FF * 2);
    __bf16* featT   = (__bf16*)(ws + (size_t)KS * NN * FF * 2 + (size_t)KS * NN * 4);

    transpose_kernel<<<NN / 64, 256, 0, stream>>>(feat, featT);
    main_kernel<<<(NN / MROWS) * KS, 256, 0, stream>>>(adj, featT, partN, partDeg);
    epilogue_kernel<<<NN / 64, 256, 0, stream>>>(feat, W, partN, partDeg, out);
}

// Round 2
// 375.210 us; speedup vs baseline: 1.0886x; 1.0886x over previous
//
#include <hip/hip_runtime.h>

#define NN 8192
#define FF 64
#define NOUT 64
#define KS 8               // K-split: grid = 128 mtiles * 8 = 1024 blocks, 4/CU resident
#define KCHUNK (NN / KS)   // 1024
#define MROWS 64           // rows per block (16 per wave)
#define TILE_K 128         // rolling LDS tile of featT
#define NTILES (KCHUNK / TILE_K)   // 8
#define BUFB (64 * TILE_K * 2)     // 16384 B per LDS buffer

typedef __bf16 bf16x8 __attribute__((ext_vector_type(8)));
typedef float f32x4 __attribute__((ext_vector_type(4)));

__device__ inline bf16x8 cvt8(f32x4 a, f32x4 b) {
    bf16x8 r;
    #pragma unroll
    for (int i = 0; i < 4; ++i) { r[i] = (__bf16)a[i]; r[i + 4] = (__bf16)b[i]; }
    return r;
}

// One-shot: featT[f][n] = bf16(feat[n][f]).  1 MB output.
__global__ __launch_bounds__(256)
void transpose_kernel(const float* __restrict__ feat, __bf16* __restrict__ featT) {
    __shared__ __bf16 t[64][72];   // +8 pad
    int tid = threadIdx.x;
    int n0 = blockIdx.x * 64;
    {
        int r = tid >> 2, cg = (tid & 3) * 16;
        const float* p = feat + (size_t)(n0 + r) * FF + cg;
        f32x4 v0 = *(const f32x4*)(p);
        f32x4 v1 = *(const f32x4*)(p + 4);
        f32x4 v2 = *(const f32x4*)(p + 8);
        f32x4 v3 = *(const f32x4*)(p + 12);
        #pragma unroll
        for (int j = 0; j < 4; ++j) {
            t[r][cg + 0 + j]  = (__bf16)v0[j];
            t[r][cg + 4 + j]  = (__bf16)v1[j];
            t[r][cg + 8 + j]  = (__bf16)v2[j];
            t[r][cg + 12 + j] = (__bf16)v3[j];
        }
    }
    __syncthreads();
    int f = tid >> 2, seg = (tid & 3) * 16;
    bf16x8 o0, o1;
    #pragma unroll
    for (int i = 0; i < 8; ++i) { o0[i] = t[seg + i][f]; o1[i] = t[seg + 8 + i][f]; }
    *(bf16x8*)&featT[(size_t)f * NN + n0 + seg]     = o0;
    *(bf16x8*)&featT[(size_t)f * NN + n0 + seg + 8] = o1;
}

// adj streamed once (nontemporal). B held in LDS, staged from bf16 featT in
// rolling double-buffered 128-k tiles (XOR-swizzled: 8 lanes/16B-column floor
// on both ds_write_b128 and ds_read_b128). One barrier per tile; next tile's
// global loads issued before compute so latency hides under 20 MFMAs.
__global__ __launch_bounds__(256, 4)
void main_kernel(const float* __restrict__ adj, const __bf16* __restrict__ featT,
                 __bf16* __restrict__ partN, float* __restrict__ partDeg) {
    __shared__ __bf16 bt[2][64 * TILE_K];   // 2 x 16 KB
    int tid = threadIdx.x;
    int w = tid >> 6, lane = tid & 63, ln = lane & 15, q = lane >> 4;
    int ks = blockIdx.x & (KS - 1);   // blk%8 == XCD -> featT slice L2-local per XCD
    int mt = blockIdx.x >> 3;         // 128 m-tiles of 64 rows

    // ---- staging thread mapping: row sr (0..63), 4 16B-blocks per thread ----
    int sr = tid >> 2;
    int scb = (tid & 3) * 4;          // block base within 16 blocks of 16B
    const __bf16* sp = featT + (size_t)sr * NN + (size_t)ks * KCHUNK;
    char* swb = (char*)&bt[0][0];
    int swoff[4];
    #pragma unroll
    for (int j = 0; j < 4; ++j)
        swoff[j] = sr * 256 + (((scb + j) ^ (sr & 7)) * 16);   // XOR swizzle

    int rowA = mt * MROWS + w * 16 + ln;
    const float* ap = adj + (size_t)rowA * NN + (size_t)ks * KCHUNK + q * 8;

    f32x4 acc[4], accd;
    accd = 0;
    #pragma unroll
    for (int t = 0; t < 4; ++t) acc[t] = 0;

    bf16x8 ones;
    __bf16 o = (ln == 0) ? (__bf16)1.0f : (__bf16)0.0f;
    #pragma unroll
    for (int i = 0; i < 8; ++i) ones[i] = o;

    // read-side swizzled byte offsets (row = ln+16g, block = s*4+q)
    int rbase0 = (ln +  0) * 256, rbase1 = (ln + 16) * 256;
    int rbase2 = (ln + 32) * 256, rbase3 = (ln + 48) * 256;
    int lx = ln & 7;

    // ---- prologue: stage tile 0 ----
    bf16x8 stg[4];
    #pragma unroll
    for (int j = 0; j < 4; ++j) stg[j] = *(const bf16x8*)(sp + (scb + j) * 8);
    #pragma unroll
    for (int j = 0; j < 4; ++j) *(bf16x8*)(swb + swoff[j]) = stg[j];
    __syncthreads();

    for (int t = 0; t < NTILES; ++t) {
        if (t + 1 < NTILES) {   // issue next tile's loads early (latency under MFMAs)
            #pragma unroll
            for (int j = 0; j < 4; ++j)
                stg[j] = *(const bf16x8*)(sp + (t + 1) * TILE_K + (scb + j) * 8);
        }
        const char* rb = (const char*)&bt[0][0] + (t & 1) * BUFB;
        const float* at = ap + t * TILE_K;
        #pragma unroll
        for (int s = 0; s < 4; ++s) {
            f32x4 a0 = __builtin_nontemporal_load((const f32x4*)(at + s * 32));
            f32x4 a1 = __builtin_nontemporal_load((const f32x4*)(at + s * 32 + 4));
            int blk = ((s * 4 + q) ^ lx) * 16;
            bf16x8 b0 = *(const bf16x8*)(rb + rbase0 + blk);
            bf16x8 b1 = *(const bf16x8*)(rb + rbase1 + blk);
            bf16x8 b2 = *(const bf16x8*)(rb + rbase2 + blk);
            bf16x8 b3 = *(const bf16x8*)(rb + rbase3 + blk);
            bf16x8 af = cvt8(a0, a1);
            acc[0] = __builtin_amdgcn_mfma_f32_16x16x32_bf16(af, b0, acc[0], 0, 0, 0);
            acc[1] = __builtin_amdgcn_mfma_f32_16x16x32_bf16(af, b1, acc[1], 0, 0, 0);
            acc[2] = __builtin_amdgcn_mfma_f32_16x16x32_bf16(af, b2, acc[2], 0, 0, 0);
            acc[3] = __builtin_amdgcn_mfma_f32_16x16x32_bf16(af, b3, acc[3], 0, 0, 0);
            accd   = __builtin_amdgcn_mfma_f32_16x16x32_bf16(af, ones, accd, 0, 0, 0);
        }
        if (t + 1 < NTILES) {
            char* wb = swb + ((t + 1) & 1) * BUFB;
            #pragma unroll
            for (int j = 0; j < 4; ++j) *(bf16x8*)(wb + swoff[j]) = stg[j];
            __syncthreads();   // writes visible before tile t+1 reads
        }
    }

    // C/D layout: col = ln, row(within 16-tile) = q*4 + r
    int grow = mt * MROWS + w * 16 + q * 4;
    #pragma unroll
    for (int r = 0; r < 4; ++r) {
        size_t base = ((size_t)(ks << 13) + grow + r) * FF + ln;
        partN[base +  0] = (__bf16)acc[0][r];
        partN[base + 16] = (__bf16)acc[1][r];
        partN[base + 32] = (__bf16)acc[2][r];
        partN[base + 48] = (__bf16)acc[3][r];
    }
    if (ln == 0) {
        #pragma unroll
        for (int r = 0; r < 4; ++r)
            partDeg[(ks << 13) + grow + r] = accd[r];
    }
}

// out = [feat | (sum_ks partN)/(sum_ks partDeg + 1)] @ W^T  via bf16 MFMA
__global__ __launch_bounds__(256)
void epilogue_kernel(const float* __restrict__ feat, const float* __restrict__ W,
                     const __bf16* __restrict__ partN, const float* __restrict__ partDeg,
                     float* __restrict__ out) {
    __shared__ __bf16 dataB[64][136];
    __shared__ float rdeg[64];
    int tid = threadIdx.x, blk = blockIdx.x;

    if (tid < 64) {
        float s = 0.f;
        #pragma unroll
        for (int ks = 0; ks < KS; ++ks) s += partDeg[(ks << 13) + blk * 64 + tid];
        rdeg[tid] = 1.0f / (s + 1.0f);
    }
    __syncthreads();

    #pragma unroll
    for (int i = 0; i < 2; ++i) {
        int idx = tid + i * 256;
        int r = idx >> 3, c = (idx & 7) * 8;
        float s[8];
        #pragma unroll
        for (int j = 0; j < 8; ++j) s[j] = 0.f;
        #pragma unroll
        for (int ks = 0; ks < KS; ++ks) {
            bf16x8 v = *(const bf16x8*)&partN[((size_t)(ks << 13) + blk * 64 + r) * FF + c];
            #pragma unroll
            for (int j = 0; j < 8; ++j) s[j] += (float)v[j];
        }
        float rd = rdeg[r];
        bf16x8 o;
        #pragma unroll
        for (int j = 0; j < 8; ++j) o[j] = (__bf16)(s[j] * rd);
        *(bf16x8*)&dataB[r][64 + c] = o;
    }
    #pragma unroll
    for (int i = 0; i < 2; ++i) {
        int idx = tid + i * 256;
        int r = idx >> 3, c = (idx & 7) * 8;
        const float* p = feat + (size_t)(blk * 64 + r) * FF + c;
        f32x4 f0 = *(const f32x4*)p;
        f32x4 f1 = *(const f32x4*)(p + 4);
        *(bf16x8*)&dataB[r][c] = cvt8(f0, f1);
    }
    __syncthreads();

    int w = tid >> 6, lane = tid & 63, ln = lane & 15, q = lane >> 4;
    f32x4 acc[4];
    #pragma unroll
    for (int t = 0; t < 4; ++t) acc[t] = 0;

    #pragma unroll
    for (int kk = 0; kk < 4; ++kk) {
        bf16x8 af = *(const bf16x8*)&dataB[w * 16 + ln][kk * 32 + q * 8];
        #pragma unroll
        for (int t = 0; t < 4; ++t) {
            const float* wp = W + (size_t)(t * 16 + ln) * 128 + kk * 32 + q * 8;
            f32x4 b0 = *(const f32x4*)wp;
            f32x4 b1 = *(const f32x4*)(wp + 4);
            bf16x8 bf = cvt8(b0, b1);
            acc[t] = __builtin_amdgcn_mfma_f32_16x16x32_bf16(af, bf, acc[t], 0, 0, 0);
        }
    }

    int grow = blk * 64 + w * 16 + q * 4;
    #pragma unroll
    for (int t = 0; t < 4; ++t)
        #pragma unroll
        for (int r = 0; r < 4; ++r)
            out[(size_t)(grow + r) * NOUT + t * 16 + ln] = acc[t][r];
}

extern "C" void kernel_launch(void* const* d_in, const int* in_sizes, int n_in,
                              void* d_out, int out_size, void* d_ws, size_t ws_size,
                              hipStream_t stream) {
    const float* adj  = (const float*)d_in[0];
    const float* feat = (const float*)d_in[1];
    const float* W    = (const float*)d_in[2];
    float* out = (float*)d_out;
    char* ws = (char*)d_ws;

    // ws: partN 8MB (KS*8192*64 bf16) | partDeg 256KB | featT 1MB
    __bf16* partN   = (__bf16*)ws;
    float*  partDeg = (float*)(ws + (size_t)KS * NN * FF * 2);
    __bf16* featT   = (__bf16*)(ws + (size_t)KS * NN * FF * 2 + (size_t)KS * NN * 4);

    transpose_kernel<<<NN / 64, 256, 0, stream>>>(feat, featT);
    main_kernel<<<(NN / MROWS) * KS, 256, 0, stream>>>(adj, featT, partN, partDeg);
    epilogue_kernel<<<NN / 64, 256, 0, stream>>>(feat, W, partN, partDeg, out);
}

// Round 3
// 370.249 us; speedup vs baseline: 1.1031x; 1.0134x over previous
//
#include <hip/hip_runtime.h>

#define NN 8192
#define FF 64
#define NOUT 64
#define KS 8               // K-split: grid = 128 mtiles * 8 = 1024 blocks, 4/CU resident
#define KCHUNK (NN / KS)   // 1024
#define MROWS 64           // rows per block (16 per wave)
#define TILE_K 128         // rolling LDS tile of featT
#define NTILES (KCHUNK / TILE_K)   // 8
#define BUFB (64 * TILE_K * 2)     // 16384 B per LDS buffer

typedef __bf16 bf16x8 __attribute__((ext_vector_type(8)));
typedef float f32x4 __attribute__((ext_vector_type(4)));

__device__ inline bf16x8 cvt8(f32x4 a, f32x4 b) {
    bf16x8 r;
    #pragma unroll
    for (int i = 0; i < 4; ++i) { r[i] = (__bf16)a[i]; r[i + 4] = (__bf16)b[i]; }
    return r;
}

// One-shot: featT[f][n] = bf16(feat[n][f]).  1 MB output.
__global__ __launch_bounds__(256)
void transpose_kernel(const float* __restrict__ feat, __bf16* __restrict__ featT) {
    __shared__ __bf16 t[64][72];   // +8 pad
    int tid = threadIdx.x;
    int n0 = blockIdx.x * 64;
    {
        int r = tid >> 2, cg = (tid & 3) * 16;
        const float* p = feat + (size_t)(n0 + r) * FF + cg;
        f32x4 v0 = *(const f32x4*)(p);
        f32x4 v1 = *(const f32x4*)(p + 4);
        f32x4 v2 = *(const f32x4*)(p + 8);
        f32x4 v3 = *(const f32x4*)(p + 12);
        #pragma unroll
        for (int j = 0; j < 4; ++j) {
            t[r][cg + 0 + j]  = (__bf16)v0[j];
            t[r][cg + 4 + j]  = (__bf16)v1[j];
            t[r][cg + 8 + j]  = (__bf16)v2[j];
            t[r][cg + 12 + j] = (__bf16)v3[j];
        }
    }
    __syncthreads();
    int f = tid >> 2, seg = (tid & 3) * 16;
    bf16x8 o0, o1;
    #pragma unroll
    for (int i = 0; i < 8; ++i) { o0[i] = t[seg + i][f]; o1[i] = t[seg + 8 + i][f]; }
    *(bf16x8*)&featT[(size_t)f * NN + n0 + seg]     = o0;
    *(bf16x8*)&featT[(size_t)f * NN + n0 + seg + 8] = o1;
}

// adj streamed once (nontemporal). B in LDS, double-buffered 128-k tiles from
// bf16 featT (XOR-swizzled, conflict-free). K-traversal DE-PHASED to break HBM
// channel camping on the 32KB row stride: per-block tile rotation (mt&7) and
// per-wave s rotation ((s+w)&3). Sum over k is order-independent.
__global__ __launch_bounds__(256, 4)
void main_kernel(const float* __restrict__ adj, const __bf16* __restrict__ featT,
                 __bf16* __restrict__ partN, float* __restrict__ partDeg) {
    __shared__ __bf16 bt[2][64 * TILE_K];   // 2 x 16 KB
    int tid = threadIdx.x;
    int w = tid >> 6, lane = tid & 63, ln = lane & 15, q = lane >> 4;
    int ks = blockIdx.x & (KS - 1);   // blk%8 == XCD -> featT slice L2-local per XCD
    int mt = blockIdx.x >> 3;         // 128 m-tiles of 64 rows

    // ---- staging thread mapping: row sr (0..63), 4 16B-blocks per thread ----
    int sr = tid >> 2;
    int scb = (tid & 3) * 4;          // block base within 16 blocks of 16B
    const __bf16* sp = featT + (size_t)sr * NN + (size_t)ks * KCHUNK;
    char* swb = (char*)&bt[0][0];
    int swoff[4];
    #pragma unroll
    for (int j = 0; j < 4; ++j)
        swoff[j] = sr * 256 + (((scb + j) ^ (sr & 7)) * 16);   // XOR swizzle

    int rowA = mt * MROWS + w * 16 + ln;
    const float* ap = adj + (size_t)rowA * NN + (size_t)ks * KCHUNK + q * 8;

    f32x4 acc[4], accd;
    accd = 0;
    #pragma unroll
    for (int t = 0; t < 4; ++t) acc[t] = 0;

    bf16x8 ones;
    __bf16 o = (ln == 0) ? (__bf16)1.0f : (__bf16)0.0f;
    #pragma unroll
    for (int i = 0; i < 8; ++i) ones[i] = o;

    // read-side swizzled byte offsets (row = ln+16g, block = srot*4+q)
    int rbase0 = (ln +  0) * 256, rbase1 = (ln + 16) * 256;
    int rbase2 = (ln + 32) * 256, rbase3 = (ln + 48) * 256;
    int lx = ln & 7;

    int trot = mt & (NTILES - 1);     // per-block k-phase rotation

    // ---- prologue: stage tile trot ----
    bf16x8 stg[4];
    #pragma unroll
    for (int j = 0; j < 4; ++j)
        stg[j] = *(const bf16x8*)(sp + trot * TILE_K + (scb + j) * 8);
    #pragma unroll
    for (int j = 0; j < 4; ++j) *(bf16x8*)(swb + swoff[j]) = stg[j];
    __syncthreads();

    for (int i = 0; i < NTILES; ++i) {
        int tt = (trot + i) & (NTILES - 1);
        if (i + 1 < NTILES) {   // issue next tile's featT loads early
            int tn = (trot + i + 1) & (NTILES - 1);
            #pragma unroll
            for (int j = 0; j < 4; ++j)
                stg[j] = *(const bf16x8*)(sp + tn * TILE_K + (scb + j) * 8);
        }
        const char* rb = (const char*)&bt[0][0] + (i & 1) * BUFB;
        const float* at = ap + tt * TILE_K;

        // hoist all 8 adj loads (12 vmem in flight/wave incl. staging)
        f32x4 a[4][2];
        #pragma unroll
        for (int s = 0; s < 4; ++s) {
            int srot = (s + w) & 3;   // per-wave column de-phasing
            a[s][0] = __builtin_nontemporal_load((const f32x4*)(at + srot * 32));
            a[s][1] = __builtin_nontemporal_load((const f32x4*)(at + srot * 32 + 4));
        }
        #pragma unroll
        for (int s = 0; s < 4; ++s) {
            int srot = (s + w) & 3;
            int blk = ((srot * 4 + q) ^ lx) * 16;
            bf16x8 b0 = *(const bf16x8*)(rb + rbase0 + blk);
            bf16x8 b1 = *(const bf16x8*)(rb + rbase1 + blk);
            bf16x8 b2 = *(const bf16x8*)(rb + rbase2 + blk);
            bf16x8 b3 = *(const bf16x8*)(rb + rbase3 + blk);
            bf16x8 af = cvt8(a[s][0], a[s][1]);
            acc[0] = __builtin_amdgcn_mfma_f32_16x16x32_bf16(af, b0, acc[0], 0, 0, 0);
            acc[1] = __builtin_amdgcn_mfma_f32_16x16x32_bf16(af, b1, acc[1], 0, 0, 0);
            acc[2] = __builtin_amdgcn_mfma_f32_16x16x32_bf16(af, b2, acc[2], 0, 0, 0);
            acc[3] = __builtin_amdgcn_mfma_f32_16x16x32_bf16(af, b3, acc[3], 0, 0, 0);
            accd   = __builtin_amdgcn_mfma_f32_16x16x32_bf16(af, ones, accd, 0, 0, 0);
        }
        if (i + 1 < NTILES) {
            char* wb = swb + ((i + 1) & 1) * BUFB;
            #pragma unroll
            for (int j = 0; j < 4; ++j) *(bf16x8*)(wb + swoff[j]) = stg[j];
            __syncthreads();   // writes visible before next tile reads
        }
    }

    // C/D layout: col = ln, row(within 16-tile) = q*4 + r
    int grow = mt * MROWS + w * 16 + q * 4;
    #pragma unroll
    for (int r = 0; r < 4; ++r) {
        size_t base = ((size_t)(ks << 13) + grow + r) * FF + ln;
        partN[base +  0] = (__bf16)acc[0][r];
        partN[base + 16] = (__bf16)acc[1][r];
        partN[base + 32] = (__bf16)acc[2][r];
        partN[base + 48] = (__bf16)acc[3][r];
    }
    if (ln == 0) {
        #pragma unroll
        for (int r = 0; r < 4; ++r)
            partDeg[(ks << 13) + grow + r] = accd[r];
    }
}

// out = [feat | (sum_ks partN)/(sum_ks partDeg + 1)] @ W^T  via bf16 MFMA
__global__ __launch_bounds__(256)
void epilogue_kernel(const float* __restrict__ feat, const float* __restrict__ W,
                     const __bf16* __restrict__ partN, const float* __restrict__ partDeg,
                     float* __restrict__ out) {
    __shared__ __bf16 dataB[64][136];
    __shared__ float rdeg[64];
    int tid = threadIdx.x, blk = blockIdx.x;

    if (tid < 64) {
        float s = 0.f;
        #pragma unroll
        for (int ks = 0; ks < KS; ++ks) s += partDeg[(ks << 13) + blk * 64 + tid];
        rdeg[tid] = 1.0f / (s + 1.0f);
    }
    __syncthreads();

    #pragma unroll
    for (int i = 0; i < 2; ++i) {
        int idx = tid + i * 256;
        int r = idx >> 3, c = (idx & 7) * 8;
        float s[8];
        #pragma unroll
        for (int j = 0; j < 8; ++j) s[j] = 0.f;
        #pragma unroll
        for (int ks = 0; ks < KS; ++ks) {
            bf16x8 v = *(const bf16x8*)&partN[((size_t)(ks << 13) + blk * 64 + r) * FF + c];
            #pragma unroll
            for (int j = 0; j < 8; ++j) s[j] += (float)v[j];
        }
        float rd = rdeg[r];
        bf16x8 o;
        #pragma unroll
        for (int j = 0; j < 8; ++j) o[j] = (__bf16)(s[j] * rd);
        *(bf16x8*)&dataB[r][64 + c] = o;
    }
    #pragma unroll
    for (int i = 0; i < 2; ++i) {
        int idx = tid + i * 256;
        int r = idx >> 3, c = (idx & 7) * 8;
        const float* p = feat + (size_t)(blk * 64 + r) * FF + c;
        f32x4 f0 = *(const f32x4*)p;
        f32x4 f1 = *(const f32x4*)(p + 4);
        *(bf16x8*)&dataB[r][c] = cvt8(f0, f1);
    }
    __syncthreads();

    int w = tid >> 6, lane = tid & 63, ln = lane & 15, q = lane >> 4;
    f32x4 acc[4];
    #pragma unroll
    for (int t = 0; t < 4; ++t) acc[t] = 0;

    #pragma unroll
    for (int kk = 0; kk < 4; ++kk) {
        bf16x8 af = *(const bf16x8*)&dataB[w * 16 + ln][kk * 32 + q * 8];
        #pragma unroll
        for (int t = 0; t < 4; ++t) {
            const float* wp = W + (size_t)(t * 16 + ln) * 128 + kk * 32 + q * 8;
            f32x4 b0 = *(const f32x4*)wp;
            f32x4 b1 = *(const f32x4*)(wp + 4);
            bf16x8 bf = cvt8(b0, b1);
            acc[t] = __builtin_amdgcn_mfma_f32_16x16x32_bf16(af, bf, acc[t], 0, 0, 0);
        }
    }

    int grow = blk * 64 + w * 16 + q * 4;
    #pragma unroll
    for (int t = 0; t < 4; ++t)
        #pragma unroll
        for (int r = 0; r < 4; ++r)
            out[(size_t)(grow + r) * NOUT + t * 16 + ln] = acc[t][r];
}

extern "C" void kernel_launch(void* const* d_in, const int* in_sizes, int n_in,
                              void* d_out, int out_size, void* d_ws, size_t ws_size,
                              hipStream_t stream) {
    const float* adj  = (const float*)d_in[0];
    const float* feat = (const float*)d_in[1];
    const float* W    = (const float*)d_in[2];
    float* out = (float*)d_out;
    char* ws = (char*)d_ws;

    // ws: partN 8MB (KS*8192*64 bf16) | partDeg 256KB | featT 1MB
    __bf16* partN   = (__bf16*)ws;
    float*  partDeg = (float*)(ws + (size_t)KS * NN * FF * 2);
    __bf16* featT   = (__bf16*)(ws + (size_t)KS * NN * FF * 2 + (size_t)KS * NN * 4);

    transpose_kernel<<<NN / 64, 256, 0, stream>>>(feat, featT);
    main_kernel<<<(NN / MROWS) * KS, 256, 0, stream>>>(adj, featT, partN, partDeg);
    epilogue_kernel<<<NN / 64, 256, 0, stream>>>(feat, W, partN, partDeg, out);
}